// Round 8
// baseline (893.381 us; speedup 1.0000x reference)
//
#include <hip/hip_runtime.h>
#include <math.h>

#define NUM_CLASSES_ 100
#define C1_ 101
#define BQ_ 3200      // B*Q = 16*200
#define QDIM_ 200
#define ROW_DW 64     // padded row: 256 B = 64 dwords

typedef __attribute__((ext_vector_type(4))) int i32x4;

// ---------------- init: acc, tc sentinel, bucket counters ----------------
__global__ void init_kernel(float* acc, int* tc, int* cnt, int nb) {
    int i = blockIdx.x * blockDim.x + threadIdx.x;
    if (i < 4) acc[i] = 0.0f;
    if (i < BQ_) tc[i] = -1;
    if (i < nb) cnt[i] = 0;
}

// ---------------- target scatter (last-write-wins) + pair histogram ----------------
__global__ void scatter_hist_kernel(const int* __restrict__ targets,
                                    const int* __restrict__ idx_b,
                                    const int* __restrict__ idx_q,
                                    int* tc, int M,
                                    const int2* __restrict__ pairs2,
                                    int* cnt, int shift, int P) {
    int t = blockIdx.x * blockDim.x + threadIdx.x;
    if (t < M) {
        int slot = idx_b[t] * QDIM_ + idx_q[t];
        atomicMax(&tc[slot], (t << 8) | targets[t]);
    }
    int stride = gridDim.x * blockDim.x;
    for (int p = t; p < P; p += stride)
        atomicAdd(&cnt[pairs2[p].x >> shift], 1);
}

// ---------------- exclusive prefix over <=256 buckets -> cursors ----------------
__global__ void prefix_kernel(const int* __restrict__ cnt, int* cursor, int nb) {
    __shared__ int s[256];
    int tid = threadIdx.x;
    int v = (tid < nb) ? cnt[tid] : 0;
    s[tid] = v;
    __syncthreads();
    #pragma unroll
    for (int off = 1; off < 256; off <<= 1) {
        int t = (tid >= off) ? s[tid - off] : 0;
        __syncthreads();
        s[tid] += t;
        __syncthreads();
    }
    if (tid < nb) cursor[tid] = s[tid] - v;   // exclusive base
}

// ---------------- scatter pairs into bucket-sorted arrays ----------------
__global__ void scatter_pairs_kernel(const int2* __restrict__ pairs2,
                                     const int* __restrict__ pos,
                                     const float* __restrict__ pw,
                                     int* cursor, int shift,
                                     int2* __restrict__ sp,
                                     int* __restrict__ spos,
                                     float* __restrict__ spw, int P) {
    int t = blockIdx.x * blockDim.x + threadIdx.x;
    int stride = gridDim.x * blockDim.x;
    for (int p = t; p < P; p += stride) {
        int2 pr = pairs2[p];
        int slot = atomicAdd(&cursor[pr.x >> shift], 1);
        sp[slot] = pr;
        spos[slot] = pos[p];
        spw[slot] = pw[p];
    }
}

// ---------------- fused quantize (blocks [0,QB)) + weighted CE (blocks [QB,QB+200)) ----------------
__global__ __launch_bounds__(256) void quant_ce_kernel(const float* __restrict__ src,
                                                       unsigned int* __restrict__ qtab,
                                                       float* __restrict__ invq, int npts,
                                                       const float* __restrict__ logits,
                                                       const int* __restrict__ tc,
                                                       const float* __restrict__ empty_w,
                                                       float* acc, int qblocks) {
    int lane = threadIdx.x & 63;
    if ((int)blockIdx.x < qblocks) {
        int gw = (blockIdx.x * blockDim.x + threadIdx.x) >> 6;
        int nw = (qblocks * blockDim.x) >> 6;
        for (int r = gw; r < npts; r += nw) {
            float4 a = make_float4(0.f, 0.f, 0.f, 0.f);
            float s = 0.0f;
            if (lane < QDIM_ / 4) {
                a = reinterpret_cast<const float4*>(src + (size_t)r * QDIM_)[lane];
                s = a.x * a.x + a.y * a.y + a.z * a.z + a.w * a.w;
            }
            #pragma unroll
            for (int off = 32; off; off >>= 1) s += __shfl_xor(s, off);
            float inv = rsqrtf(s);
            inv = inv * (1.5f - 0.5f * s * inv * inv);   // Newton -> fp32-accurate
            float sc = inv * 127.0f;
            int q0 = (int)rintf(a.x * sc);
            int q1 = (int)rintf(a.y * sc);
            int q2 = (int)rintf(a.z * sc);
            int q3 = (int)rintf(a.w * sc);
            unsigned int packed = (unsigned)(q0 & 255) | ((unsigned)(q1 & 255) << 8)
                                | ((unsigned)(q2 & 255) << 16) | ((unsigned)(q3 & 255) << 24);
            int sq = q0 * q0 + q1 * q1 + q2 * q2 + q3 * q3;
            #pragma unroll
            for (int off = 32; off; off >>= 1) sq += __shfl_xor(sq, off);
            qtab[(size_t)r * ROW_DW + lane] = (lane < QDIM_ / 4) ? packed : 0u;
            if (lane == 0) {
                float fs = (float)sq;                 // < 2^24, exact
                float iv = rsqrtf(fs);
                iv = iv * (1.5f - 0.5f * fs * iv * iv);
                invq[r] = iv;
            }
        }
    } else {
        int bid = blockIdx.x - qblocks;
        int gw = (bid * blockDim.x + threadIdx.x) >> 6;
        int nw = (200 * blockDim.x) >> 6;
        float lnum = 0.0f, lden = 0.0f;
        for (int row = gw; row < BQ_; row += nw) {
            const float* x = logits + (size_t)row * C1_;
            float x0 = x[lane];
            bool has2 = (lane < C1_ - 64);
            float x1 = has2 ? x[lane + 64] : -INFINITY;
            float m = fmaxf(x0, x1);
            #pragma unroll
            for (int off = 32; off; off >>= 1) m = fmaxf(m, __shfl_xor(m, off));
            float s = expf(x0 - m) + (has2 ? expf(x1 - m) : 0.0f);
            #pragma unroll
            for (int off = 32; off; off >>= 1) s += __shfl_xor(s, off);
            int packed = tc[row];
            int cls = (packed >= 0) ? (packed & 255) : NUM_CLASSES_;
            float xt = x[cls];
            float nll = -(xt - m - logf(s));
            float w = empty_w[cls];
            lnum += w * nll;
            lden += w;
        }
        if (lane == 0) { atomicAdd(&acc[0], lnum); atomicAdd(&acc[1], lden); }
    }
}

// ---------------- cluster loss: int8 MFMA, depth-2 pipeline, XCD-contiguous chunks ----------------
__global__ __launch_bounds__(256) void pair_mfma_kernel(const uint4* __restrict__ qtab4,
                                                        const int2* __restrict__ pairs2,
                                                        const int* __restrict__ pos,
                                                        const float* __restrict__ pw,
                                                        const float* __restrict__ invq,
                                                        float* acc, int P) {
    int lane = threadIdx.x & 63;
    int i15 = lane & 15;
    int grp = lane >> 4;
    int wib = threadIdx.x >> 6;
    int nchunks = (P + 15) / 16;

    // XCD-contiguous chunk range: sorted pairs -> x-rows stay hot in this XCD's L2
    int xcd = blockIdx.x & 7;
    int lb  = blockIdx.x >> 3;                    // 0..255 for grid 2048
    int lw  = lb * 4 + wib;                       // 0..1023 local wave
    int lnw = ((gridDim.x >> 3) * blockDim.x) >> 6;   // 1024
    int nxc = (nchunks + 7) / 8;
    int cbeg = xcd * nxc;
    int cend = min(nchunks, cbeg + nxc);

    int myreg = i15 - (grp << 2);                 // diag ownership
    bool owns = (myreg >= 0) && (myreg < 4);

    float num = 0.0f, den = 0.0f;

    int pA; uint4 a0A, a1A, a2A, a3A, b0A, b1A, b2A, b3A; int posA; float pwA, iqA;
    int pB; uint4 a0B, a1B, a2B, a3B, b0B, b1B, b2B, b3B; int posB; float pwB, iqB;

    auto loadA = [&](int c) {
        pA = c * 16 + i15;
        int pc = min(pA, P - 1);
        int2 pr = pairs2[pc];
        const uint4* ar = qtab4 + (size_t)pr.x * 16;
        const uint4* br = qtab4 + (size_t)pr.y * 16;
        a0A = ar[grp]; a1A = ar[4 + grp]; a2A = ar[8 + grp]; a3A = ar[12 + grp];
        b0A = br[grp]; b1A = br[4 + grp]; b2A = br[8 + grp]; b3A = br[12 + grp];
        posA = pos[pc]; pwA = pw[pc];
        iqA = invq[pr.x] * invq[pr.y];
    };
    auto loadB = [&](int c) {
        pB = c * 16 + i15;
        int pc = min(pB, P - 1);
        int2 pr = pairs2[pc];
        const uint4* ar = qtab4 + (size_t)pr.x * 16;
        const uint4* br = qtab4 + (size_t)pr.y * 16;
        a0B = ar[grp]; a1B = ar[4 + grp]; a2B = ar[8 + grp]; a3B = ar[12 + grp];
        b0B = br[grp]; b1B = br[4 + grp]; b2B = br[8 + grp]; b3B = br[12 + grp];
        posB = pos[pc]; pwB = pw[pc];
        iqB = invq[pr.x] * invq[pr.y];
    };
    auto procA = [&]() {
        i32x4 macc = {0, 0, 0, 0};
        macc = __builtin_amdgcn_mfma_i32_16x16x64_i8(*(i32x4*)&a0A, *(i32x4*)&b0A, macc, 0, 0, 0);
        macc = __builtin_amdgcn_mfma_i32_16x16x64_i8(*(i32x4*)&a1A, *(i32x4*)&b1A, macc, 0, 0, 0);
        macc = __builtin_amdgcn_mfma_i32_16x16x64_i8(*(i32x4*)&a2A, *(i32x4*)&b2A, macc, 0, 0, 0);
        macc = __builtin_amdgcn_mfma_i32_16x16x64_i8(*(i32x4*)&a3A, *(i32x4*)&b3A, macc, 0, 0, 0);
        if (owns && pA < P) {
            int d = (myreg == 0) ? macc[0] : (myreg == 1) ? macc[1]
                  : (myreg == 2) ? macc[2] : macc[3];
            float cosv = (float)d * iqA;
            float per = posA ? (1.0f - cosv) : fmaxf(cosv, 0.0f);
            float w = fmaxf(pwA, 0.1f);
            num += w * per;
            den += w;
        }
    };
    auto procB = [&]() {
        i32x4 macc = {0, 0, 0, 0};
        macc = __builtin_amdgcn_mfma_i32_16x16x64_i8(*(i32x4*)&a0B, *(i32x4*)&b0B, macc, 0, 0, 0);
        macc = __builtin_amdgcn_mfma_i32_16x16x64_i8(*(i32x4*)&a1B, *(i32x4*)&b1B, macc, 0, 0, 0);
        macc = __builtin_amdgcn_mfma_i32_16x16x64_i8(*(i32x4*)&a2B, *(i32x4*)&b2B, macc, 0, 0, 0);
        macc = __builtin_amdgcn_mfma_i32_16x16x64_i8(*(i32x4*)&a3B, *(i32x4*)&b3B, macc, 0, 0, 0);
        if (owns && pB < P) {
            int d = (myreg == 0) ? macc[0] : (myreg == 1) ? macc[1]
                  : (myreg == 2) ? macc[2] : macc[3];
            float cosv = (float)d * iqB;
            float per = posB ? (1.0f - cosv) : fmaxf(cosv, 0.0f);
            float w = fmaxf(pwB, 0.1f);
            num += w * per;
            den += w;
        }
    };

    int c = cbeg + lw;
    if (c < cend) {
        loadA(c);
        for (;;) {
            int cB = c + lnw;
            bool hasB = (cB < cend);
            if (hasB) loadB(cB);
            procA();
            if (!hasB) break;
            int cA = cB + lnw;
            bool hasA = (cA < cend);
            if (hasA) loadA(cA);
            procB();
            if (!hasA) break;
            c = cA;
        }
    }

    #pragma unroll
    for (int off = 32; off; off >>= 1) {
        num += __shfl_xor(num, off);
        den += __shfl_xor(den, off);
    }
    __shared__ float snum[4], sden[4];
    if (lane == 0) { snum[wib] = num; sden[wib] = den; }
    __syncthreads();
    if (threadIdx.x == 0) {
        atomicAdd(&acc[2], snum[0] + snum[1] + snum[2] + snum[3]);
        atomicAdd(&acc[3], sden[0] + sden[1] + sden[2] + sden[3]);
    }
}

// ---------------- fp32 fallback path (ws too small) ----------------
__global__ __launch_bounds__(256) void ce_kernel(const float* __restrict__ logits,
                                                 const int* __restrict__ tc,
                                                 const float* __restrict__ empty_w,
                                                 float* acc) {
    int lane = threadIdx.x & 63;
    int gw = (blockIdx.x * blockDim.x + threadIdx.x) >> 6;
    int nw = (gridDim.x * blockDim.x) >> 6;
    float lnum = 0.0f, lden = 0.0f;
    for (int row = gw; row < BQ_; row += nw) {
        const float* x = logits + (size_t)row * C1_;
        float x0 = x[lane];
        bool has2 = (lane < C1_ - 64);
        float x1 = has2 ? x[lane + 64] : -INFINITY;
        float m = fmaxf(x0, x1);
        #pragma unroll
        for (int off = 32; off; off >>= 1) m = fmaxf(m, __shfl_xor(m, off));
        float s = expf(x0 - m) + (has2 ? expf(x1 - m) : 0.0f);
        #pragma unroll
        for (int off = 32; off; off >>= 1) s += __shfl_xor(s, off);
        int packed = tc[row];
        int cls = (packed >= 0) ? (packed & 255) : NUM_CLASSES_;
        float xt = x[cls];
        float nll = -(xt - m - logf(s));
        float w = empty_w[cls];
        lnum += w * nll;
        lden += w;
    }
    if (lane == 0) { atomicAdd(&acc[0], lnum); atomicAdd(&acc[1], lden); }
}

__global__ __launch_bounds__(256) void pair_fp32_kernel(const float* __restrict__ src,
                                                        const int* __restrict__ pairs,
                                                        const int* __restrict__ pos,
                                                        const float* __restrict__ pw,
                                                        float* acc, int P) {
    int lane = threadIdx.x & 63;
    int gw = (blockIdx.x * blockDim.x + threadIdx.x) >> 6;
    int nw = (gridDim.x * blockDim.x) >> 6;
    float num = 0.0f, den = 0.0f;
    for (int p = gw; p < P; p += nw) {
        int2 pr = reinterpret_cast<const int2*>(pairs)[p];
        float dot = 0.0f, saa = 0.0f, sbb = 0.0f;
        if (lane < QDIM_ / 4) {
            float4 a = reinterpret_cast<const float4*>(src + (size_t)pr.x * QDIM_)[lane];
            float4 b = reinterpret_cast<const float4*>(src + (size_t)pr.y * QDIM_)[lane];
            dot = a.x * b.x + a.y * b.y + a.z * b.z + a.w * b.w;
            saa = a.x * a.x + a.y * a.y + a.z * a.z + a.w * a.w;
            sbb = b.x * b.x + b.y * b.y + b.z * b.z + b.w * b.w;
        }
        #pragma unroll
        for (int off = 32; off; off >>= 1) {
            dot += __shfl_xor(dot, off);
            saa += __shfl_xor(saa, off);
            sbb += __shfl_xor(sbb, off);
        }
        float cosv = dot / (sqrtf(saa) * sqrtf(sbb) + 1e-8f);
        float per = pos[p] ? (1.0f - cosv) : fmaxf(cosv, 0.0f);
        float w = fmaxf(pw[p], 0.1f);
        num += w * per;
        den += w;
    }
    __shared__ float snum[4], sden[4];
    int wib = threadIdx.x >> 6;
    if (lane == 0) { snum[wib] = num; sden[wib] = den; }
    __syncthreads();
    if (threadIdx.x == 0) {
        atomicAdd(&acc[2], snum[0] + snum[1] + snum[2] + snum[3]);
        atomicAdd(&acc[3], sden[0] + sden[1] + sden[2] + sden[3]);
    }
}

// ---------------- combine ----------------
__global__ void final_kernel(const float* __restrict__ acc, float* out) {
    if (threadIdx.x == 0 && blockIdx.x == 0)
        out[0] = acc[0] / acc[1] + acc[2] / acc[3];
}

extern "C" void kernel_launch(void* const* d_in, const int* in_sizes, int n_in,
                              void* d_out, int out_size, void* d_ws, size_t ws_size,
                              hipStream_t stream) {
    const float* pred_logits = (const float*)d_in[0];
    const int*   targets     = (const int*)d_in[1];
    const int*   idx_b       = (const int*)d_in[2];
    const int*   idx_q       = (const int*)d_in[3];
    const float* src         = (const float*)d_in[4];
    const int*   pairs       = (const int*)d_in[5];
    const int*   pair_pos    = (const int*)d_in[6];
    const float* pair_w      = (const float*)d_in[7];
    const float* empty_w     = (const float*)d_in[8];
    float* out = (float*)d_out;

    int M = in_sizes[1];
    int P = in_sizes[7];
    int npts = in_sizes[4] / QDIM_;

    // bucket shift: <=256 buckets over npts rows
    int shift = 10;
    while (((npts + (1 << shift) - 1) >> shift) > 256) shift++;
    int nb = (npts + (1 << shift) - 1) >> shift;

    // ws layout
    float* acc    = (float*)d_ws;                                 // 16 B
    int*   tc     = (int*)((char*)d_ws + 64);                     // 12.8 KB
    int*   cnt    = (int*)((char*)d_ws + 16384);                  // 1 KB
    int*   cursor = (int*)((char*)d_ws + 20480);                  // 1 KB
    int2*  sp     = (int2*)((char*)d_ws + 32768);                 // 8P
    int*   spos   = (int*)((char*)d_ws + (size_t)4194304 + (size_t)4 * P);
    float* spw    = (float*)((char*)d_ws + (size_t)8388608 + (size_t)8 * P);
    unsigned int* qtab = (unsigned int*)((char*)d_ws + 16777216);     // 256-B aligned
    float* invq   = (float*)((char*)d_ws + 16777216 + (size_t)npts * 256);

    size_t need = (size_t)16777216 + (size_t)npts * 256 + (size_t)npts * 4;
    bool fast = ws_size >= need && (size_t)P * 16 + 8388608 <= 16777216;

    if (fast) {
        init_kernel<<<(BQ_ + 255) / 256, 256, 0, stream>>>(acc, tc, cnt, nb);
        scatter_hist_kernel<<<2048, 256, 0, stream>>>(targets, idx_b, idx_q, tc, M,
                                                      (const int2*)pairs, cnt, shift, P);
        prefix_kernel<<<1, 256, 0, stream>>>(cnt, cursor, nb);
        scatter_pairs_kernel<<<2048, 256, 0, stream>>>((const int2*)pairs, pair_pos, pair_w,
                                                       cursor, shift, sp, spos, spw, P);
        quant_ce_kernel<<<2048 + 200, 256, 0, stream>>>(src, qtab, invq, npts,
                                                        pred_logits, tc, empty_w, acc, 2048);
        pair_mfma_kernel<<<2048, 256, 0, stream>>>((const uint4*)qtab, (const int2*)sp,
                                                   spos, spw, invq, acc, P);
    } else {
        init_kernel<<<(BQ_ + 255) / 256, 256, 0, stream>>>(acc, tc, cnt, nb);
        scatter_hist_kernel<<<8, 256, 0, stream>>>(targets, idx_b, idx_q, tc, M,
                                                   (const int2*)pairs, cnt, shift, 0);
        ce_kernel<<<200, 256, 0, stream>>>(pred_logits, tc, empty_w, acc);
        pair_fp32_kernel<<<2048, 256, 0, stream>>>(src, pairs, pair_pos, pair_w, acc, P);
    }
    final_kernel<<<1, 64, 0, stream>>>(acc, out);
}

// Round 11
// 333.405 us; speedup vs baseline: 2.6796x; 2.6796x over previous
//
#include <hip/hip_runtime.h>
#include <math.h>

#define NUM_CLASSES_ 100
#define C1_ 101
#define BQ_ 3200      // B*Q = 16*200
#define QDIM_ 200

typedef __attribute__((ext_vector_type(4))) int i32x4;

// ---------------- init: zero accumulators, set target-class map sentinel ----------------
__global__ void init_kernel(float* acc, int* tc) {
    int i = blockIdx.x * blockDim.x + threadIdx.x;
    if (i < 4) acc[i] = 0.0f;
    if (i < BQ_) tc[i] = -1;
}

// ---------------- scatter targets, last-write-wins (numpy semantics) ----------------
__global__ void scatter_kernel(const int* __restrict__ targets,
                               const int* __restrict__ idx_b,
                               const int* __restrict__ idx_q,
                               int* tc, int M) {
    int m = blockIdx.x * blockDim.x + threadIdx.x;
    if (m < M) {
        int slot = idx_b[m] * QDIM_ + idx_q[m];
        atomicMax(&tc[slot], (m << 8) | targets[m]);
    }
}

// ---------------- fused int4-quantize (blocks [0,QB)) + weighted CE (blocks [QB,QB+200)) -------
// Row layout (128 B): 50 ushorts of 4 biased nibbles (elems 0..199), ushorts 50..59 = 0x8888
// (pad elems, biased zero), bytes 120..127 = {int Sq, float invq} metadata (never fed to MFMA).
__global__ __launch_bounds__(256) void quant_ce_kernel(const float* __restrict__ src,
                                                       unsigned short* __restrict__ qtab16,
                                                       int npts,
                                                       const float* __restrict__ logits,
                                                       const int* __restrict__ tc,
                                                       const float* __restrict__ empty_w,
                                                       float* acc, int qblocks) {
    int lane = threadIdx.x & 63;
    if ((int)blockIdx.x < qblocks) {
        int gw = (blockIdx.x * blockDim.x + threadIdx.x) >> 6;
        int nw = (qblocks * blockDim.x) >> 6;
        for (int r = gw; r < npts; r += nw) {
            float4 a = make_float4(0.f, 0.f, 0.f, 0.f);
            float mx = 0.0f;
            if (lane < QDIM_ / 4) {
                a = reinterpret_cast<const float4*>(src + (size_t)r * QDIM_)[lane];
                mx = fmaxf(fmaxf(fabsf(a.x), fabsf(a.y)), fmaxf(fabsf(a.z), fabsf(a.w)));
            }
            #pragma unroll
            for (int off = 32; off; off >>= 1) mx = fmaxf(mx, __shfl_xor(mx, off));
            float sc = (mx > 0.0f) ? 7.0f / mx : 0.0f;      // per-row adaptive int4 scale
            int q0 = (int)rintf(a.x * sc);
            int q1 = (int)rintf(a.y * sc);
            int q2 = (int)rintf(a.z * sc);
            int q3 = (int)rintf(a.w * sc);
            int sq = q0 * q0 + q1 * q1 + q2 * q2 + q3 * q3;
            int qs = q0 + q1 + q2 + q3;
            #pragma unroll
            for (int off = 32; off; off >>= 1) {
                sq += __shfl_xor(sq, off);
                qs += __shfl_xor(qs, off);
            }
            unsigned short h = (unsigned short)(((q0 + 8) & 15) | (((q1 + 8) & 15) << 4)
                              | (((q2 + 8) & 15) << 8) | (((q3 + 8) & 15) << 12));
            unsigned short* row = qtab16 + (size_t)r * 64;
            if (lane < 50)      row[lane] = h;
            else if (lane < 60) row[lane] = 0x8888;          // biased-zero pad
            else if (lane == 60) {
                float fs = (float)sq;                        // < 2^24, exact
                float iv = 0.0f;
                if (sq > 0) {
                    iv = rsqrtf(fs);
                    iv = iv * (1.5f - 0.5f * fs * iv * iv);  // Newton -> fp32-accurate
                }
                int2 m; m.x = qs; m.y = __float_as_int(iv);
                reinterpret_cast<int2*>(row)[15] = m;        // bytes 120..127
            }
        }
    } else {
        int bid = blockIdx.x - qblocks;
        int gw = (bid * blockDim.x + threadIdx.x) >> 6;
        int nw = (200 * blockDim.x) >> 6;
        float lnum = 0.0f, lden = 0.0f;
        for (int row = gw; row < BQ_; row += nw) {
            const float* x = logits + (size_t)row * C1_;
            float x0 = x[lane];
            bool has2 = (lane < C1_ - 64);
            float x1 = has2 ? x[lane + 64] : -INFINITY;
            float m = fmaxf(x0, x1);
            #pragma unroll
            for (int off = 32; off; off >>= 1) m = fmaxf(m, __shfl_xor(m, off));
            float s = expf(x0 - m) + (has2 ? expf(x1 - m) : 0.0f);
            #pragma unroll
            for (int off = 32; off; off >>= 1) s += __shfl_xor(s, off);
            int packed = tc[row];
            int cls = (packed >= 0) ? (packed & 255) : NUM_CLASSES_;
            float xt = x[cls];
            float nll = -(xt - m - logf(s));
            float w = empty_w[cls];
            lnum += w * nll;
            lden += w;
        }
        if (lane == 0) { atomicAdd(&acc[0], lnum); atomicAdd(&acc[1], lden); }
    }
}

// ---------------- cluster loss: int4 rows + i8 MFMA, depth-2 chunk pipeline ----------------
// Lane l: pair i = l&15, k-group g = l>>4. 4x mfma_i32_16x16x64_i8 over K=256 biased bytes.
// D_diag = Σ s_a s_b; dot = D - 8(Sa+Sb) - 16384 (exact). Diagonal is permutation/transpose-
// invariant, so nibble interleave and fragment layout don't affect correctness.
__global__ __launch_bounds__(256) void pair_i4_kernel(const uint2* __restrict__ qtab2,
                                                      const int2* __restrict__ pairs2,
                                                      const int* __restrict__ pos,
                                                      const float* __restrict__ pw,
                                                      float* acc, int P) {
    int lane = threadIdx.x & 63;
    int i15 = lane & 15;
    int grp = lane >> 4;
    int gw = (blockIdx.x * blockDim.x + threadIdx.x) >> 6;
    int nw = (gridDim.x * blockDim.x) >> 6;
    int nchunks = (P + 15) / 16;

    int myreg = i15 - (grp << 2);                 // diag ownership
    bool owns = (myreg >= 0) && (myreg < 4);
    const uint2 PADV = make_uint2(0x88888888u, 0x88888888u);

    float num = 0.0f, den = 0.0f;

    int pA; uint2 a0A, a1A, a2A, a3A, b0A, b1A, b2A, b3A; int posA; float pwA, iqA, corrA;
    int pB; uint2 a0B, a1B, a2B, a3B, b0B, b1B, b2B, b3B; int posB; float pwB, iqB, corrB;

    auto loadA = [&](int c) {
        pA = c * 16 + i15;
        int pc = min(pA, P - 1);
        int2 pr = pairs2[pc];
        const uint2* ar = qtab2 + (size_t)pr.x * 16;   // 128-B row = 16 uint2
        const uint2* br = qtab2 + (size_t)pr.y * 16;
        a0A = ar[grp];     b0A = br[grp];
        a1A = ar[4 + grp]; b1A = br[4 + grp];
        a2A = ar[8 + grp]; b2A = br[8 + grp];
        a3A = (grp == 0) ? ar[12] : PADV;              // slice 3: only g0 has real elems
        b3A = (grp == 0) ? br[12] : PADV;
        int2 mx = reinterpret_cast<const int2*>(ar)[15];   // meta rides in row's 2nd line
        int2 my = reinterpret_cast<const int2*>(br)[15];
        iqA = __int_as_float(mx.y) * __int_as_float(my.y);
        corrA = (float)(8 * (mx.x + my.x) + 16384);
        posA = pos[pc]; pwA = pw[pc];
    };
    auto loadB = [&](int c) {
        pB = c * 16 + i15;
        int pc = min(pB, P - 1);
        int2 pr = pairs2[pc];
        const uint2* ar = qtab2 + (size_t)pr.x * 16;
        const uint2* br = qtab2 + (size_t)pr.y * 16;
        a0B = ar[grp];     b0B = br[grp];
        a1B = ar[4 + grp]; b1B = br[4 + grp];
        a2B = ar[8 + grp]; b2B = br[8 + grp];
        a3B = (grp == 0) ? ar[12] : PADV;
        b3B = (grp == 0) ? br[12] : PADV;
        int2 mx = reinterpret_cast<const int2*>(ar)[15];
        int2 my = reinterpret_cast<const int2*>(br)[15];
        iqB = __int_as_float(mx.y) * __int_as_float(my.y);
        corrB = (float)(8 * (mx.x + my.x) + 16384);
        posB = pos[pc]; pwB = pw[pc];
    };
    auto UNP = [](uint2 v) -> i32x4 {
        i32x4 r;
        r[0] = (int)(v.x & 0x0F0F0F0Fu);
        r[1] = (int)((v.x >> 4) & 0x0F0F0F0Fu);
        r[2] = (int)(v.y & 0x0F0F0F0Fu);
        r[3] = (int)((v.y >> 4) & 0x0F0F0F0Fu);
        return r;
    };
    auto procA = [&]() {
        i32x4 macc = {0, 0, 0, 0};
        macc = __builtin_amdgcn_mfma_i32_16x16x64_i8(UNP(a0A), UNP(b0A), macc, 0, 0, 0);
        macc = __builtin_amdgcn_mfma_i32_16x16x64_i8(UNP(a1A), UNP(b1A), macc, 0, 0, 0);
        macc = __builtin_amdgcn_mfma_i32_16x16x64_i8(UNP(a2A), UNP(b2A), macc, 0, 0, 0);
        macc = __builtin_amdgcn_mfma_i32_16x16x64_i8(UNP(a3A), UNP(b3A), macc, 0, 0, 0);
        if (owns && pA < P) {
            int d = (myreg == 0) ? macc[0] : (myreg == 1) ? macc[1]
                  : (myreg == 2) ? macc[2] : macc[3];
            float cosv = ((float)d - corrA) * iqA;
            float per = posA ? (1.0f - cosv) : fmaxf(cosv, 0.0f);
            float w = fmaxf(pwA, 0.1f);
            num += w * per;
            den += w;
        }
    };
    auto procB = [&]() {
        i32x4 macc = {0, 0, 0, 0};
        macc = __builtin_amdgcn_mfma_i32_16x16x64_i8(UNP(a0B), UNP(b0B), macc, 0, 0, 0);
        macc = __builtin_amdgcn_mfma_i32_16x16x64_i8(UNP(a1B), UNP(b1B), macc, 0, 0, 0);
        macc = __builtin_amdgcn_mfma_i32_16x16x64_i8(UNP(a2B), UNP(b2B), macc, 0, 0, 0);
        macc = __builtin_amdgcn_mfma_i32_16x16x64_i8(UNP(a3B), UNP(b3B), macc, 0, 0, 0);
        if (owns && pB < P) {
            int d = (myreg == 0) ? macc[0] : (myreg == 1) ? macc[1]
                  : (myreg == 2) ? macc[2] : macc[3];
            float cosv = ((float)d - corrB) * iqB;
            float per = posB ? (1.0f - cosv) : fmaxf(cosv, 0.0f);
            float w = fmaxf(pwB, 0.1f);
            num += w * per;
            den += w;
        }
    };

    if (gw < nchunks) {
        loadA(gw);
        int c = gw;
        for (;;) {
            int cB = c + nw;
            bool hasB = (cB < nchunks);
            if (hasB) loadB(cB);
            procA();
            if (!hasB) break;
            int cA = cB + nw;
            bool hasA = (cA < nchunks);
            if (hasA) loadA(cA);
            procB();
            if (!hasA) break;
            c = cA;
        }
    }

    #pragma unroll
    for (int off = 32; off; off >>= 1) {
        num += __shfl_xor(num, off);
        den += __shfl_xor(den, off);
    }
    __shared__ float snum[4], sden[4];
    int wib = threadIdx.x >> 6;
    if (lane == 0) { snum[wib] = num; sden[wib] = den; }
    __syncthreads();
    if (threadIdx.x == 0) {
        atomicAdd(&acc[2], snum[0] + snum[1] + snum[2] + snum[3]);
        atomicAdd(&acc[3], sden[0] + sden[1] + sden[2] + sden[3]);
    }
}

// ---------------- fp32 fallback path (ws too small) ----------------
__global__ __launch_bounds__(256) void ce_kernel(const float* __restrict__ logits,
                                                 const int* __restrict__ tc,
                                                 const float* __restrict__ empty_w,
                                                 float* acc) {
    int lane = threadIdx.x & 63;
    int gw = (blockIdx.x * blockDim.x + threadIdx.x) >> 6;
    int nw = (gridDim.x * blockDim.x) >> 6;
    float lnum = 0.0f, lden = 0.0f;
    for (int row = gw; row < BQ_; row += nw) {
        const float* x = logits + (size_t)row * C1_;
        float x0 = x[lane];
        bool has2 = (lane < C1_ - 64);
        float x1 = has2 ? x[lane + 64] : -INFINITY;
        float m = fmaxf(x0, x1);
        #pragma unroll
        for (int off = 32; off; off >>= 1) m = fmaxf(m, __shfl_xor(m, off));
        float s = expf(x0 - m) + (has2 ? expf(x1 - m) : 0.0f);
        #pragma unroll
        for (int off = 32; off; off >>= 1) s += __shfl_xor(s, off);
        int packed = tc[row];
        int cls = (packed >= 0) ? (packed & 255) : NUM_CLASSES_;
        float xt = x[cls];
        float nll = -(xt - m - logf(s));
        float w = empty_w[cls];
        lnum += w * nll;
        lden += w;
    }
    if (lane == 0) { atomicAdd(&acc[0], lnum); atomicAdd(&acc[1], lden); }
}

__global__ __launch_bounds__(256) void pair_fp32_kernel(const float* __restrict__ src,
                                                        const int* __restrict__ pairs,
                                                        const int* __restrict__ pos,
                                                        const float* __restrict__ pw,
                                                        float* acc, int P) {
    int lane = threadIdx.x & 63;
    int gw = (blockIdx.x * blockDim.x + threadIdx.x) >> 6;
    int nw = (gridDim.x * blockDim.x) >> 6;
    float num = 0.0f, den = 0.0f;
    for (int p = gw; p < P; p += nw) {
        int2 pr = reinterpret_cast<const int2*>(pairs)[p];
        float dot = 0.0f, saa = 0.0f, sbb = 0.0f;
        if (lane < QDIM_ / 4) {
            float4 a = reinterpret_cast<const float4*>(src + (size_t)pr.x * QDIM_)[lane];
            float4 b = reinterpret_cast<const float4*>(src + (size_t)pr.y * QDIM_)[lane];
            dot = a.x * b.x + a.y * b.y + a.z * b.z + a.w * b.w;
            saa = a.x * a.x + a.y * a.y + a.z * a.z + a.w * a.w;
            sbb = b.x * b.x + b.y * b.y + b.z * b.z + b.w * b.w;
        }
        #pragma unroll
        for (int off = 32; off; off >>= 1) {
            dot += __shfl_xor(dot, off);
            saa += __shfl_xor(saa, off);
            sbb += __shfl_xor(sbb, off);
        }
        float cosv = dot / (sqrtf(saa) * sqrtf(sbb) + 1e-8f);
        float per = pos[p] ? (1.0f - cosv) : fmaxf(cosv, 0.0f);
        float w = fmaxf(pw[p], 0.1f);
        num += w * per;
        den += w;
    }
    __shared__ float snum[4], sden[4];
    int wib = threadIdx.x >> 6;
    if (lane == 0) { snum[wib] = num; sden[wib] = den; }
    __syncthreads();
    if (threadIdx.x == 0) {
        atomicAdd(&acc[2], snum[0] + snum[1] + snum[2] + snum[3]);
        atomicAdd(&acc[3], sden[0] + sden[1] + sden[2] + sden[3]);
    }
}

// ---------------- combine ----------------
__global__ void final_kernel(const float* __restrict__ acc, float* out) {
    if (threadIdx.x == 0 && blockIdx.x == 0)
        out[0] = acc[0] / acc[1] + acc[2] / acc[3];
}

extern "C" void kernel_launch(void* const* d_in, const int* in_sizes, int n_in,
                              void* d_out, int out_size, void* d_ws, size_t ws_size,
                              hipStream_t stream) {
    const float* pred_logits = (const float*)d_in[0];
    const int*   targets     = (const int*)d_in[1];
    const int*   idx_b       = (const int*)d_in[2];
    const int*   idx_q       = (const int*)d_in[3];
    const float* src         = (const float*)d_in[4];
    const int*   pairs       = (const int*)d_in[5];
    const int*   pair_pos    = (const int*)d_in[6];
    const float* pair_w      = (const float*)d_in[7];
    const float* empty_w     = (const float*)d_in[8];
    float* out = (float*)d_out;

    int M = in_sizes[1];
    int P = in_sizes[7];
    int npts = in_sizes[4] / QDIM_;

    float* acc = (float*)d_ws;                                      // 16 B
    int*   tc  = (int*)((char*)d_ws + 64);                          // 12.8 KB
    unsigned short* qtab16 = (unsigned short*)((char*)d_ws + 16384);// npts x 128 B rows (meta embedded)

    init_kernel<<<(BQ_ + 255) / 256, 256, 0, stream>>>(acc, tc);
    scatter_kernel<<<(M + 255) / 256, 256, 0, stream>>>(targets, idx_b, idx_q, tc, M);

    bool fast = ws_size >= (size_t)16384 + (size_t)npts * 128;
    if (fast) {
        quant_ce_kernel<<<2048 + 200, 256, 0, stream>>>(src, qtab16, npts,
                                                        pred_logits, tc, empty_w, acc, 2048);
        pair_i4_kernel<<<2048, 256, 0, stream>>>((const uint2*)qtab16, (const int2*)pairs,
                                                 pair_pos, pair_w, acc, P);
    } else {
        ce_kernel<<<200, 256, 0, stream>>>(pred_logits, tc, empty_w, acc);
        pair_fp32_kernel<<<2048, 256, 0, stream>>>(src, pairs, pair_pos, pair_w, acc, P);
    }
    final_kernel<<<1, 64, 0, stream>>>(acc, out);
}

// Round 12
// 327.456 us; speedup vs baseline: 2.7282x; 1.0182x over previous
//
#include <hip/hip_runtime.h>
#include <math.h>

#define NUM_CLASSES_ 100
#define C1_ 101
#define BQ_ 3200      // B*Q = 16*200
#define QDIM_ 200

typedef __attribute__((ext_vector_type(4))) int i32x4;

// ---------------- init: zero accumulators, set target-class map sentinel ----------------
__global__ void init_kernel(float* acc, int* tc) {
    int i = blockIdx.x * blockDim.x + threadIdx.x;
    if (i < 4) acc[i] = 0.0f;
    if (i < BQ_) tc[i] = -1;
}

// ---------------- scatter targets, last-write-wins (numpy semantics) ----------------
__global__ void scatter_kernel(const int* __restrict__ targets,
                               const int* __restrict__ idx_b,
                               const int* __restrict__ idx_q,
                               int* tc, int M) {
    int m = blockIdx.x * blockDim.x + threadIdx.x;
    if (m < M) {
        int slot = idx_b[m] * QDIM_ + idx_q[m];
        atomicMax(&tc[slot], (m << 8) | targets[m]);
    }
}

// ---------------- fused int4-quantize (blocks [0,QB)) + weighted CE (blocks [QB,QB+200)) -------
// GROUP-MAJOR row layout (128 B): uint2 unit u = grp*4 + slice; lane-group grp's 4 slices are
// contiguous 32 B -> pair kernel reads each row side with 2x dwordx4. Element e=4l maps to
// ushort slot ((g*4+s)*4)|(l&3) with s=l>>4, g=(l>>2)&3 (bijection over 64 lanes).
// Meta {qs, invq} lives in a separate 8B/row array (L2-resident).
__global__ __launch_bounds__(256) void quant_ce_kernel(const float* __restrict__ src,
                                                       unsigned short* __restrict__ qtab16,
                                                       int2* __restrict__ meta,
                                                       int npts,
                                                       const float* __restrict__ logits,
                                                       const int* __restrict__ tc,
                                                       const float* __restrict__ empty_w,
                                                       float* acc, int qblocks) {
    int lane = threadIdx.x & 63;
    if ((int)blockIdx.x < qblocks) {
        int gw = (blockIdx.x * blockDim.x + threadIdx.x) >> 6;
        int nw = (qblocks * blockDim.x) >> 6;
        int s4 = lane >> 4;
        int g4 = (lane >> 2) & 3;
        int uidx = ((g4 * 4 + s4) << 2) | (lane & 3);    // ushort slot in group-major row
        for (int r = gw; r < npts; r += nw) {
            float4 a = make_float4(0.f, 0.f, 0.f, 0.f);
            float mx = 0.0f;
            if (lane < QDIM_ / 4) {
                a = reinterpret_cast<const float4*>(src + (size_t)r * QDIM_)[lane];
                mx = fmaxf(fmaxf(fabsf(a.x), fabsf(a.y)), fmaxf(fabsf(a.z), fabsf(a.w)));
            }
            #pragma unroll
            for (int off = 32; off; off >>= 1) mx = fmaxf(mx, __shfl_xor(mx, off));
            float sc = (mx > 0.0f) ? 7.0f / mx : 0.0f;      // per-row adaptive int4 scale
            int q0 = (int)rintf(a.x * sc);
            int q1 = (int)rintf(a.y * sc);
            int q2 = (int)rintf(a.z * sc);
            int q3 = (int)rintf(a.w * sc);
            int sq = q0 * q0 + q1 * q1 + q2 * q2 + q3 * q3;
            int qs = q0 + q1 + q2 + q3;
            #pragma unroll
            for (int off = 32; off; off >>= 1) {
                sq += __shfl_xor(sq, off);
                qs += __shfl_xor(qs, off);
            }
            unsigned short h = (unsigned short)(((q0 + 8) & 15) | (((q1 + 8) & 15) << 4)
                              | (((q2 + 8) & 15) << 8) | (((q3 + 8) & 15) << 12));
            unsigned short* row = qtab16 + (size_t)r * 64;
            row[uidx] = (lane < 50) ? h : (unsigned short)0x8888;   // pads = biased zero
            if (lane == 0) {
                float fs = (float)sq;                        // < 2^24, exact
                float iv = 0.0f;
                if (sq > 0) {
                    iv = rsqrtf(fs);
                    iv = iv * (1.5f - 0.5f * fs * iv * iv);  // Newton -> fp32-accurate
                }
                int2 m; m.x = qs; m.y = __float_as_int(iv);
                meta[r] = m;
            }
        }
    } else {
        int bid = blockIdx.x - qblocks;
        int gw = (bid * blockDim.x + threadIdx.x) >> 6;
        int nw = (200 * blockDim.x) >> 6;
        float lnum = 0.0f, lden = 0.0f;
        for (int row = gw; row < BQ_; row += nw) {
            const float* x = logits + (size_t)row * C1_;
            float x0 = x[lane];
            bool has2 = (lane < C1_ - 64);
            float x1 = has2 ? x[lane + 64] : -INFINITY;
            float m = fmaxf(x0, x1);
            #pragma unroll
            for (int off = 32; off; off >>= 1) m = fmaxf(m, __shfl_xor(m, off));
            float s = expf(x0 - m) + (has2 ? expf(x1 - m) : 0.0f);
            #pragma unroll
            for (int off = 32; off; off >>= 1) s += __shfl_xor(s, off);
            int packed = tc[row];
            int cls = (packed >= 0) ? (packed & 255) : NUM_CLASSES_;
            float xt = x[cls];
            float nll = -(xt - m - logf(s));
            float w = empty_w[cls];
            lnum += w * nll;
            lden += w;
        }
        if (lane == 0) { atomicAdd(&acc[0], lnum); atomicAdd(&acc[1], lden); }
    }
}

// ---------------- cluster loss: group-major int4 rows + i8 MFMA, depth-2 pipeline ----------------
// Lane l: pair i = l&15, k-group g = l>>4. Row side = 2x dwordx4 (32 B contiguous per lane).
// 4x mfma_i32_16x16x64_i8 over K=256 biased bytes; D_diag = dot + 8(Sa+Sb) + 16384 (exact).
// Diagonal is permutation/transpose-invariant -> fragment layout details cancel.
__global__ __launch_bounds__(256) void pair_i4_kernel(const uint4* __restrict__ qtab4,
                                                      const int2* __restrict__ meta,
                                                      const int2* __restrict__ pairs2,
                                                      const int* __restrict__ pos,
                                                      const float* __restrict__ pw,
                                                      float* acc, int P) {
    int lane = threadIdx.x & 63;
    int i15 = lane & 15;
    int grp = lane >> 4;
    int gw = (blockIdx.x * blockDim.x + threadIdx.x) >> 6;
    int nw = (gridDim.x * blockDim.x) >> 6;
    int nchunks = (P + 15) / 16;

    int myreg = i15 - (grp << 2);                 // diag ownership
    bool owns = (myreg >= 0) && (myreg < 4);

    float num = 0.0f, den = 0.0f;

    int pA; uint4 a0A, a1A, b0A, b1A; int posA; float pwA, iqA, corrA;
    int pB; uint4 a0B, a1B, b0B, b1B; int posB; float pwB, iqB, corrB;

    auto loadA = [&](int c) {
        pA = c * 16 + i15;
        int pc = min(pA, P - 1);
        int2 pr = pairs2[pc];
        const uint4* ar = qtab4 + (size_t)pr.x * 8 + grp * 2;   // row = 8 uint4; grp block = 2
        const uint4* br = qtab4 + (size_t)pr.y * 8 + grp * 2;
        a0A = ar[0]; a1A = ar[1];
        b0A = br[0]; b1A = br[1];
        int2 mx = meta[pr.x];
        int2 my = meta[pr.y];
        iqA = __int_as_float(mx.y) * __int_as_float(my.y);
        corrA = (float)(8 * (mx.x + my.x) + 16384);
        posA = pos[pc]; pwA = pw[pc];
    };
    auto loadB = [&](int c) {
        pB = c * 16 + i15;
        int pc = min(pB, P - 1);
        int2 pr = pairs2[pc];
        const uint4* ar = qtab4 + (size_t)pr.x * 8 + grp * 2;
        const uint4* br = qtab4 + (size_t)pr.y * 8 + grp * 2;
        a0B = ar[0]; a1B = ar[1];
        b0B = br[0]; b1B = br[1];
        int2 mx = meta[pr.x];
        int2 my = meta[pr.y];
        iqB = __int_as_float(mx.y) * __int_as_float(my.y);
        corrB = (float)(8 * (mx.x + my.x) + 16384);
        posB = pos[pc]; pwB = pw[pc];
    };
    auto UNPxy = [](uint4 v) -> i32x4 {
        i32x4 r;
        r[0] = (int)(v.x & 0x0F0F0F0Fu);
        r[1] = (int)((v.x >> 4) & 0x0F0F0F0Fu);
        r[2] = (int)(v.y & 0x0F0F0F0Fu);
        r[3] = (int)((v.y >> 4) & 0x0F0F0F0Fu);
        return r;
    };
    auto UNPzw = [](uint4 v) -> i32x4 {
        i32x4 r;
        r[0] = (int)(v.z & 0x0F0F0F0Fu);
        r[1] = (int)((v.z >> 4) & 0x0F0F0F0Fu);
        r[2] = (int)(v.w & 0x0F0F0F0Fu);
        r[3] = (int)((v.w >> 4) & 0x0F0F0F0Fu);
        return r;
    };
    auto procA = [&]() {
        i32x4 macc = {0, 0, 0, 0};
        macc = __builtin_amdgcn_mfma_i32_16x16x64_i8(UNPxy(a0A), UNPxy(b0A), macc, 0, 0, 0);
        macc = __builtin_amdgcn_mfma_i32_16x16x64_i8(UNPzw(a0A), UNPzw(b0A), macc, 0, 0, 0);
        macc = __builtin_amdgcn_mfma_i32_16x16x64_i8(UNPxy(a1A), UNPxy(b1A), macc, 0, 0, 0);
        macc = __builtin_amdgcn_mfma_i32_16x16x64_i8(UNPzw(a1A), UNPzw(b1A), macc, 0, 0, 0);
        if (owns && pA < P) {
            int d = (myreg == 0) ? macc[0] : (myreg == 1) ? macc[1]
                  : (myreg == 2) ? macc[2] : macc[3];
            float cosv = ((float)d - corrA) * iqA;
            float per = posA ? (1.0f - cosv) : fmaxf(cosv, 0.0f);
            float w = fmaxf(pwA, 0.1f);
            num += w * per;
            den += w;
        }
    };
    auto procB = [&]() {
        i32x4 macc = {0, 0, 0, 0};
        macc = __builtin_amdgcn_mfma_i32_16x16x64_i8(UNPxy(a0B), UNPxy(b0B), macc, 0, 0, 0);
        macc = __builtin_amdgcn_mfma_i32_16x16x64_i8(UNPzw(a0B), UNPzw(b0B), macc, 0, 0, 0);
        macc = __builtin_amdgcn_mfma_i32_16x16x64_i8(UNPxy(a1B), UNPxy(b1B), macc, 0, 0, 0);
        macc = __builtin_amdgcn_mfma_i32_16x16x64_i8(UNPzw(a1B), UNPzw(b1B), macc, 0, 0, 0);
        if (owns && pB < P) {
            int d = (myreg == 0) ? macc[0] : (myreg == 1) ? macc[1]
                  : (myreg == 2) ? macc[2] : macc[3];
            float cosv = ((float)d - corrB) * iqB;
            float per = posB ? (1.0f - cosv) : fmaxf(cosv, 0.0f);
            float w = fmaxf(pwB, 0.1f);
            num += w * per;
            den += w;
        }
    };

    if (gw < nchunks) {
        loadA(gw);
        int c = gw;
        for (;;) {
            int cB = c + nw;
            bool hasB = (cB < nchunks);
            if (hasB) loadB(cB);
            procA();
            if (!hasB) break;
            int cA = cB + nw;
            bool hasA = (cA < nchunks);
            if (hasA) loadA(cA);
            procB();
            if (!hasA) break;
            c = cA;
        }
    }

    #pragma unroll
    for (int off = 32; off; off >>= 1) {
        num += __shfl_xor(num, off);
        den += __shfl_xor(den, off);
    }
    __shared__ float snum[4], sden[4];
    int wib = threadIdx.x >> 6;
    if (lane == 0) { snum[wib] = num; sden[wib] = den; }
    __syncthreads();
    if (threadIdx.x == 0) {
        atomicAdd(&acc[2], snum[0] + snum[1] + snum[2] + snum[3]);
        atomicAdd(&acc[3], sden[0] + sden[1] + sden[2] + sden[3]);
    }
}

// ---------------- fp32 fallback path (ws too small) ----------------
__global__ __launch_bounds__(256) void ce_kernel(const float* __restrict__ logits,
                                                 const int* __restrict__ tc,
                                                 const float* __restrict__ empty_w,
                                                 float* acc) {
    int lane = threadIdx.x & 63;
    int gw = (blockIdx.x * blockDim.x + threadIdx.x) >> 6;
    int nw = (gridDim.x * blockDim.x) >> 6;
    float lnum = 0.0f, lden = 0.0f;
    for (int row = gw; row < BQ_; row += nw) {
        const float* x = logits + (size_t)row * C1_;
        float x0 = x[lane];
        bool has2 = (lane < C1_ - 64);
        float x1 = has2 ? x[lane + 64] : -INFINITY;
        float m = fmaxf(x0, x1);
        #pragma unroll
        for (int off = 32; off; off >>= 1) m = fmaxf(m, __shfl_xor(m, off));
        float s = expf(x0 - m) + (has2 ? expf(x1 - m) : 0.0f);
        #pragma unroll
        for (int off = 32; off; off >>= 1) s += __shfl_xor(s, off);
        int packed = tc[row];
        int cls = (packed >= 0) ? (packed & 255) : NUM_CLASSES_;
        float xt = x[cls];
        float nll = -(xt - m - logf(s));
        float w = empty_w[cls];
        lnum += w * nll;
        lden += w;
    }
    if (lane == 0) { atomicAdd(&acc[0], lnum); atomicAdd(&acc[1], lden); }
}

__global__ __launch_bounds__(256) void pair_fp32_kernel(const float* __restrict__ src,
                                                        const int* __restrict__ pairs,
                                                        const int* __restrict__ pos,
                                                        const float* __restrict__ pw,
                                                        float* acc, int P) {
    int lane = threadIdx.x & 63;
    int gw = (blockIdx.x * blockDim.x + threadIdx.x) >> 6;
    int nw = (gridDim.x * blockDim.x) >> 6;
    float num = 0.0f, den = 0.0f;
    for (int p = gw; p < P; p += nw) {
        int2 pr = reinterpret_cast<const int2*>(pairs)[p];
        float dot = 0.0f, saa = 0.0f, sbb = 0.0f;
        if (lane < QDIM_ / 4) {
            float4 a = reinterpret_cast<const float4*>(src + (size_t)pr.x * QDIM_)[lane];
            float4 b = reinterpret_cast<const float4*>(src + (size_t)pr.y * QDIM_)[lane];
            dot = a.x * b.x + a.y * b.y + a.z * b.z + a.w * b.w;
            saa = a.x * a.x + a.y * a.y + a.z * a.z + a.w * a.w;
            sbb = b.x * b.x + b.y * b.y + b.z * b.z + b.w * b.w;
        }
        #pragma unroll
        for (int off = 32; off; off >>= 1) {
            dot += __shfl_xor(dot, off);
            saa += __shfl_xor(saa, off);
            sbb += __shfl_xor(sbb, off);
        }
        float cosv = dot / (sqrtf(saa) * sqrtf(sbb) + 1e-8f);
        float per = pos[p] ? (1.0f - cosv) : fmaxf(cosv, 0.0f);
        float w = fmaxf(pw[p], 0.1f);
        num += w * per;
        den += w;
    }
    __shared__ float snum[4], sden[4];
    int wib = threadIdx.x >> 6;
    if (lane == 0) { snum[wib] = num; sden[wib] = den; }
    __syncthreads();
    if (threadIdx.x == 0) {
        atomicAdd(&acc[2], snum[0] + snum[1] + snum[2] + snum[3]);
        atomicAdd(&acc[3], sden[0] + sden[1] + sden[2] + sden[3]);
    }
}

// ---------------- combine ----------------
__global__ void final_kernel(const float* __restrict__ acc, float* out) {
    if (threadIdx.x == 0 && blockIdx.x == 0)
        out[0] = acc[0] / acc[1] + acc[2] / acc[3];
}

extern "C" void kernel_launch(void* const* d_in, const int* in_sizes, int n_in,
                              void* d_out, int out_size, void* d_ws, size_t ws_size,
                              hipStream_t stream) {
    const float* pred_logits = (const float*)d_in[0];
    const int*   targets     = (const int*)d_in[1];
    const int*   idx_b       = (const int*)d_in[2];
    const int*   idx_q       = (const int*)d_in[3];
    const float* src         = (const float*)d_in[4];
    const int*   pairs       = (const int*)d_in[5];
    const int*   pair_pos    = (const int*)d_in[6];
    const float* pair_w      = (const float*)d_in[7];
    const float* empty_w     = (const float*)d_in[8];
    float* out = (float*)d_out;

    int M = in_sizes[1];
    int P = in_sizes[7];
    int npts = in_sizes[4] / QDIM_;

    // ws layout: acc | tc | meta (8B/row) | qtab (128B/row, 256-B aligned region)
    float* acc  = (float*)d_ws;                                     // 16 B
    int*   tc   = (int*)((char*)d_ws + 64);                         // 12.8 KB
    int2*  meta = (int2*)((char*)d_ws + 16384);                     // npts x 8 B
    size_t qoff = 16384 + (((size_t)npts * 8 + 255) & ~(size_t)255);
    unsigned short* qtab16 = (unsigned short*)((char*)d_ws + qoff); // npts x 128 B

    init_kernel<<<(BQ_ + 255) / 256, 256, 0, stream>>>(acc, tc);
    scatter_kernel<<<(M + 255) / 256, 256, 0, stream>>>(targets, idx_b, idx_q, tc, M);

    bool fast = ws_size >= qoff + (size_t)npts * 128;
    if (fast) {
        quant_ce_kernel<<<2048 + 200, 256, 0, stream>>>(src, qtab16, meta, npts,
                                                        pred_logits, tc, empty_w, acc, 2048);
        pair_i4_kernel<<<2048, 256, 0, stream>>>((const uint4*)qtab16, meta, (const int2*)pairs,
                                                 pair_pos, pair_w, acc, P);
    } else {
        ce_kernel<<<200, 256, 0, stream>>>(pred_logits, tc, empty_w, acc);
        pair_fp32_kernel<<<2048, 256, 0, stream>>>(src, pairs, pair_pos, pair_w, acc, P);
    }
    final_kernel<<<1, 64, 0, stream>>>(acc, out);
}